// Round 2
// baseline (10005.938 us; speedup 1.0000x reference)
//
#include <hip/hip_runtime.h>
#include <stdint.h>

#define B_  128
#define T_  512
#define H_  512
#define G3  1536

typedef __attribute__((ext_vector_type(8))) short bf16x8;
typedef __attribute__((ext_vector_type(4))) short bf16x4;
typedef __attribute__((ext_vector_type(4))) float f32x4;

#define MFMA16(a,b,c) __builtin_amdgcn_mfma_f32_16x16x32_bf16((a),(b),(c),0,0,0)

__device__ __forceinline__ unsigned short f2bf(float f) {
  union { float f; unsigned u; } v; v.f = f;
  unsigned r = v.u + 0x7FFFu + ((v.u >> 16) & 1u);
  return (unsigned short)(r >> 16);
}
__device__ __forceinline__ float bf2f(unsigned short u) {
  union { unsigned u; float f; } v; v.u = ((unsigned)u) << 16; return v.f;
}
__device__ __forceinline__ float sigm_f(float x) { return 1.f / (1.f + __expf(-x)); }
__device__ __forceinline__ float tanh_f(float x) { float e = __expf(2.f * x); return 1.f - 2.f / (e + 1.f); }

// ---------------- K0: cast weights to bf16 + zero the barrier ----------------
__launch_bounds__(256)
__global__ void k_cast(const float* __restrict__ Wih_f, const float* __restrict__ Wih_b,
                       const float* __restrict__ Whh_f, const float* __restrict__ Whh_b,
                       const float* __restrict__ Wp,
                       unsigned short* __restrict__ Wih, unsigned short* __restrict__ Whh,
                       unsigned short* __restrict__ Wpb, unsigned* __restrict__ bar) {
  int idx = blockIdx.x * 256 + threadIdx.x;
  if (idx < 512) bar[idx] = 0;
  if (idx < 1572864) {            // Wih: [2][1536][512]
    float v = (idx < 786432) ? Wih_f[idx] : Wih_b[idx - 786432];
    Wih[idx] = f2bf(v);
  } else if (idx < 3145728) {     // Whh: [2][1536][512]
    int i2 = idx - 1572864;
    float v = (i2 < 786432) ? Whh_f[i2] : Whh_b[i2 - 786432];
    Whh[i2] = f2bf(v);
  } else if (idx < 3670016) {     // Wp: [512][1024]
    int i3 = idx - 3145728;
    Wpb[i3] = f2bf(Wp[i3]);
  }
}

// ---------------- K1: gather embedding -> x_bf [65536][512] ----------------
__launch_bounds__(256)
__global__ void k_gather(const int* __restrict__ tokens, const float* __restrict__ emb,
                         unsigned short* __restrict__ xbf) {
  int row = blockIdx.x * 4 + (threadIdx.x >> 6);
  int lane = threadIdx.x & 63;
  int tok = tokens[row];
  const float4* src = (const float4*)(emb + (size_t)tok * 512);
  float4 v0 = src[lane * 2], v1 = src[lane * 2 + 1];
  bf16x8 pk;
  pk[0] = (short)f2bf(v0.x); pk[1] = (short)f2bf(v0.y);
  pk[2] = (short)f2bf(v0.z); pk[3] = (short)f2bf(v0.w);
  pk[4] = (short)f2bf(v1.x); pk[5] = (short)f2bf(v1.y);
  pk[6] = (short)f2bf(v1.z); pk[7] = (short)f2bf(v1.w);
  *(bf16x8*)&xbf[(size_t)row * 512 + lane * 8] = pk;
}

// ---------------- K2: persistent bidirectional GRU recurrence ----------------
// 64 co-resident blocks: dir = blockIdx/32, each block owns 16 hidden dims.
// Per step: (1) x_t @ Wih_slice^T (h-independent, overlaps barrier), (2) wait
// for h_{t-1}, (3) h @ Whh_slice^T, (4) gates in f32, write h_t slice + out
// slice, (5) arrive at per-step counter barrier (release). Weight B-frags read
// straight from L2 (no LDS -> no static-LDS limits, trivial occupancy).
__launch_bounds__(256, 1)
__global__ void k_rec(const unsigned short* __restrict__ xbf,
                      const unsigned short* __restrict__ Wih,
                      const unsigned short* __restrict__ Whh,
                      const float* __restrict__ bih_f, const float* __restrict__ bih_b,
                      const float* __restrict__ bhh_f, const float* __restrict__ bhh_b,
                      const int* __restrict__ lengths,
                      unsigned short* __restrict__ hbuf,   // [2 buf][2 dir][128][512] bf16
                      unsigned short* __restrict__ outb,   // [65536][1024] bf16
                      unsigned* __restrict__ bar) {        // [512] per-step counters
  int tid = threadIdx.x;
  int lane = tid & 63, w = tid >> 6;
  int quad = lane >> 4, l15 = lane & 15;
  int dir = blockIdx.x >> 5;
  int j0 = (blockIdx.x & 31) << 4;
  int jg = j0 + l15;

  const unsigned short* wih_g = Wih + (size_t)dir * (G3 * H_);
  const unsigned short* whh_g = Whh + (size_t)dir * (G3 * H_);
  const float* bih = dir ? bih_b : bih_f;
  const float* bhh = dir ? bhh_b : bhh_f;
  float b_r  = bih[jg] + bhh[jg];
  float b_z  = bih[512 + jg] + bhh[512 + jg];
  float b_in = bih[1024 + jg];
  float b_hn = bhh[1024 + jg];

  // weight-slice row base pointers for B-frags (lane l15 = output dim j0+l15)
  const unsigned short* wir = wih_g + (size_t)(jg) * H_;
  const unsigned short* wiz = wih_g + (size_t)(512 + jg) * H_;
  const unsigned short* win = wih_g + (size_t)(1024 + jg) * H_;
  const unsigned short* whr = whh_g + (size_t)(jg) * H_;
  const unsigned short* whz = whh_g + (size_t)(512 + jg) * H_;
  const unsigned short* whn = whh_g + (size_t)(1024 + jg) * H_;

  int b0 = 32 * w + l15, b1 = b0 + 16;          // A-frag rows
  int L0 = lengths[b0], L1 = lengths[b1];
  int Lg[2][4];
  #pragma unroll
  for (int mt = 0; mt < 2; ++mt)
    #pragma unroll
    for (int r = 0; r < 4; ++r)
      Lg[mt][r] = lengths[32 * w + 16 * mt + 4 * quad + r];

  unsigned short* hb = hbuf + (size_t)dir * (B_ * H_);
  float hreg[2][4] = {};   // f32 master copy of own (b, j) hidden values

  for (int t = 0; t < T_; ++t) {
    const unsigned short* hc = hb + (size_t)(t & 1) * (2 * B_ * H_);
    unsigned short* hnx      = hb + (size_t)((t & 1) ^ 1) * (2 * B_ * H_);

    f32x4 acc_r[2], acc_z[2], acc_in[2], acc_hn[2];
    #pragma unroll
    for (int mt = 0; mt < 2; ++mt) {
      acc_r[mt] = (f32x4){0.f, 0.f, 0.f, 0.f};
      acc_z[mt] = (f32x4){0.f, 0.f, 0.f, 0.f};
      acc_in[mt] = (f32x4){0.f, 0.f, 0.f, 0.f};
      acc_hn[mt] = (f32x4){0.f, 0.f, 0.f, 0.f};
    }

    // ---- (1) input GEMM for step t — independent of h, overlaps stragglers
    int tx0 = dir ? ((t < L0) ? (L0 - 1 - t) : 0) : t;
    int tx1 = dir ? ((t < L1) ? (L1 - 1 - t) : 0) : t;
    const unsigned short* xr0 = xbf + ((size_t)b0 * T_ + tx0) * 512;
    const unsigned short* xr1 = xbf + ((size_t)b1 * T_ + tx1) * 512;
    for (int s = 0; s < 16; ++s) {
      int kb = s * 32 + quad * 8;
      bf16x8 ax0 = *(const bf16x8*)&xr0[kb];
      bf16x8 ax1 = *(const bf16x8*)&xr1[kb];
      bf16x8 br = *(const bf16x8*)&wir[kb];
      bf16x8 bz = *(const bf16x8*)&wiz[kb];
      bf16x8 bn = *(const bf16x8*)&win[kb];
      acc_r[0] = MFMA16(ax0, br, acc_r[0]);  acc_r[1] = MFMA16(ax1, br, acc_r[1]);
      acc_z[0] = MFMA16(ax0, bz, acc_z[0]);  acc_z[1] = MFMA16(ax1, bz, acc_z[1]);
      acc_in[0] = MFMA16(ax0, bn, acc_in[0]); acc_in[1] = MFMA16(ax1, bn, acc_in[1]);
    }

    // ---- (2) wait for h_{t-1} (all blocks arrived at bar[t-1])
    if (t > 0) {
      if (tid == 0) {
        while (__hip_atomic_load(&bar[t - 1], __ATOMIC_ACQUIRE, __HIP_MEMORY_SCOPE_AGENT) < 64u)
          __builtin_amdgcn_s_sleep(2);
      }
      __syncthreads();
      // ---- (3) hidden GEMM
      for (int s = 0; s < 16; ++s) {
        int kb = s * 32 + quad * 8;
        bf16x8 ah0 = *(const bf16x8*)&hc[(size_t)b0 * H_ + kb];
        bf16x8 ah1 = *(const bf16x8*)&hc[(size_t)b1 * H_ + kb];
        bf16x8 br = *(const bf16x8*)&whr[kb];
        bf16x8 bz = *(const bf16x8*)&whz[kb];
        bf16x8 bn = *(const bf16x8*)&whn[kb];
        acc_r[0] = MFMA16(ah0, br, acc_r[0]);  acc_r[1] = MFMA16(ah1, br, acc_r[1]);
        acc_z[0] = MFMA16(ah0, bz, acc_z[0]);  acc_z[1] = MFMA16(ah1, bz, acc_z[1]);
        acc_hn[0] = MFMA16(ah0, bn, acc_hn[0]); acc_hn[1] = MFMA16(ah1, bn, acc_hn[1]);
      }
    }

    // ---- (4) gates + state/output writes
    #pragma unroll
    for (int mt = 0; mt < 2; ++mt) {
      #pragma unroll
      for (int r = 0; r < 4; ++r) {
        int b = 32 * w + 16 * mt + 4 * quad + r;
        int L = Lg[mt][r];
        bool vld = t < L;
        float rr = sigm_f(acc_r[mt][r] + b_r);
        float zz = sigm_f(acc_z[mt][r] + b_z);
        float nn = tanh_f(acc_in[mt][r] + b_in + rr * (acc_hn[mt][r] + b_hn));
        float hold = hreg[mt][r];
        float hnew = vld ? ((1.f - zz) * nn + zz * hold) : hold;
        hreg[mt][r] = hnew;
        hnx[(size_t)b * H_ + jg] = f2bf(hnew);
        int p = dir ? (vld ? (L - 1 - t) : t) : t;
        outb[((size_t)b * T_ + p) * 1024 + dir * 512 + jg] =
            vld ? f2bf(hnew) : (unsigned short)0;
      }
    }

    // ---- (5) arrive (release: drains this block's stores, flushes L2)
    __syncthreads();
    if (tid == 0)
      __hip_atomic_fetch_add(&bar[t], 1u, __ATOMIC_RELEASE, __HIP_MEMORY_SCOPE_AGENT);
  }
}

// ---------------- K3: GEMM2 fused  sc4[cb] = sum_c tanh(out@Wp^T + bp) * ctx ----------------
__launch_bounds__(256)
__global__ void k_gemm2(const unsigned short* __restrict__ outbf,
                        const unsigned short* __restrict__ Wpb,
                        const float* __restrict__ bp, const float* __restrict__ ctx,
                        float* __restrict__ sc4) {     // [4][65536] partials
  __shared__ short smem[2 * 128 * 72];
  short* a_s = smem;
  short* b_s = smem + 128 * 72;
  int tid = threadIdx.x;
  int lane = tid & 63, w = tid >> 6;
  int quad = lane >> 4, l15 = lane & 15;
  int row0 = blockIdx.x * 128, col0 = blockIdx.y * 128;

  f32x4 acc[2][8];
  #pragma unroll
  for (int i = 0; i < 2; ++i)
    #pragma unroll
    for (int j = 0; j < 8; ++j) acc[i][j] = (f32x4){0.f, 0.f, 0.f, 0.f};

  for (int kt = 0; kt < 16; ++kt) {
    int k0 = kt * 64;
    __syncthreads();
    #pragma unroll
    for (int q = 0; q < 4; ++q) {
      int u = tid + 256 * q;
      int r = u >> 3, cu = u & 7;
      *(bf16x8*)&a_s[r * 72 + cu * 8] = *(const bf16x8*)&outbf[(size_t)(row0 + r) * 1024 + k0 + cu * 8];
      *(bf16x8*)&b_s[r * 72 + cu * 8] = *(const bf16x8*)&Wpb[(size_t)(col0 + r) * 1024 + k0 + cu * 8];
    }
    __syncthreads();
    #pragma unroll
    for (int kk = 0; kk < 2; ++kk) {
      int kb = kk * 32 + quad * 8;
      bf16x8 a0 = *(const bf16x8*)&a_s[(w * 32 + l15) * 72 + kb];
      bf16x8 a1 = *(const bf16x8*)&a_s[(w * 32 + 16 + l15) * 72 + kb];
      #pragma unroll
      for (int nt = 0; nt < 8; ++nt) {
        bf16x8 bb = *(const bf16x8*)&b_s[(nt * 16 + l15) * 72 + kb];
        acc[0][nt] = MFMA16(a0, bb, acc[0][nt]);
        acc[1][nt] = MFMA16(a1, bb, acc[1][nt]);
      }
    }
  }

  float rs[2][4] = {};
  #pragma unroll
  for (int mt = 0; mt < 2; ++mt) {
    #pragma unroll
    for (int nt = 0; nt < 8; ++nt) {
      int col = col0 + nt * 16 + l15;
      float bv = bp[col], cv = ctx[col];
      #pragma unroll
      for (int r = 0; r < 4; ++r) {
        float x = acc[mt][nt][r] + bv;
        rs[mt][r] += tanh_f(x) * cv;
      }
    }
  }
  #pragma unroll
  for (int mt = 0; mt < 2; ++mt) {
    #pragma unroll
    for (int r = 0; r < 4; ++r) {
      float v = rs[mt][r];
      v += __shfl_xor(v, 1); v += __shfl_xor(v, 2);
      v += __shfl_xor(v, 4); v += __shfl_xor(v, 8);
      if (l15 == 0)
        sc4[(size_t)blockIdx.y * 65536 + row0 + 32 * w + 16 * mt + 4 * quad + r] = v;
    }
  }
}

// ---------------- K4: masked softmax -> attn (output) ----------------
__launch_bounds__(64)
__global__ void k_softmax(const float* __restrict__ sc4, const int* __restrict__ lengths,
                          float* __restrict__ attn) {
  int b = blockIdx.x, lane = threadIdx.x;
  int L = lengths[b];
  float s[8]; float mx = -1e30f;
  #pragma unroll
  for (int i = 0; i < 8; ++i) {
    int t = lane + i * 64;
    int idx = b * T_ + t;
    float v = -1e30f;
    if (t < L)
      v = sc4[idx] + sc4[65536 + idx] + sc4[131072 + idx] + sc4[196608 + idx];
    s[i] = v;
    mx = fmaxf(mx, v);
  }
  #pragma unroll
  for (int o = 32; o; o >>= 1) mx = fmaxf(mx, __shfl_xor(mx, o));
  float sum = 0.f;
  #pragma unroll
  for (int i = 0; i < 8; ++i) {
    int t = lane + i * 64;
    s[i] = (t < L) ? __expf(s[i] - mx) : 0.f;
    sum += s[i];
  }
  #pragma unroll
  for (int o = 32; o; o >>= 1) sum += __shfl_xor(sum, o);
  float inv = 1.f / sum;
  #pragma unroll
  for (int i = 0; i < 8; ++i) attn[b * T_ + lane + i * 64] = s[i] * inv;
}

// ---------------- K5: attention pool + selu + classifier ----------------
__launch_bounds__(256)
__global__ void k_final(const float* __restrict__ attn, const unsigned short* __restrict__ outb,
                        const int* __restrict__ lengths,
                        const float* __restrict__ Wl, const float* __restrict__ bl,
                        float* __restrict__ logits) {
  __shared__ float red[8];
  int b = blockIdx.x, tid = threadIdx.x;
  int L = lengths[b];
  float a0 = 0.f, a1 = 0.f, a2 = 0.f, a3 = 0.f;
  for (int t = 0; t < L; ++t) {
    float a = attn[b * T_ + t];
    const unsigned short* row = outb + ((size_t)b * T_ + t) * 1024 + tid * 4;
    bf16x4 v = *(const bf16x4*)row;
    a0 += a * bf2f((unsigned short)v[0]);
    a1 += a * bf2f((unsigned short)v[1]);
    a2 += a * bf2f((unsigned short)v[2]);
    a3 += a * bf2f((unsigned short)v[3]);
  }
  const float al = 1.6732632423543772f, sc = 1.0507009873554805f;
  float s0 = sc * (a0 > 0.f ? a0 : al * (__expf(a0) - 1.f));
  float s1 = sc * (a1 > 0.f ? a1 : al * (__expf(a1) - 1.f));
  float s2 = sc * (a2 > 0.f ? a2 : al * (__expf(a2) - 1.f));
  float s3 = sc * (a3 > 0.f ? a3 : al * (__expf(a3) - 1.f));
  int d = tid * 4;
  float p0 = s0 * Wl[d] + s1 * Wl[d + 1] + s2 * Wl[d + 2] + s3 * Wl[d + 3];
  float p1 = s0 * Wl[1024 + d] + s1 * Wl[1024 + d + 1] + s2 * Wl[1024 + d + 2] + s3 * Wl[1024 + d + 3];
  #pragma unroll
  for (int o = 32; o; o >>= 1) { p0 += __shfl_xor(p0, o); p1 += __shfl_xor(p1, o); }
  if ((tid & 63) == 0) { red[(tid >> 6) * 2] = p0; red[(tid >> 6) * 2 + 1] = p1; }
  __syncthreads();
  if (tid == 0) {
    logits[b * 2]     = red[0] + red[2] + red[4] + red[6] + bl[0];
    logits[b * 2 + 1] = red[1] + red[3] + red[5] + red[7] + bl[1];
  }
}

// ---------------- launcher ----------------
extern "C" void kernel_launch(void* const* d_in, const int* in_sizes, int n_in,
                              void* d_out, int out_size, void* d_ws, size_t ws_size,
                              hipStream_t stream) {
  const int*   tokens  = (const int*)d_in[0];
  const int*   lengths = (const int*)d_in[1];
  const float* emb     = (const float*)d_in[2];
  const float* Wih_f   = (const float*)d_in[3];
  const float* Whh_f   = (const float*)d_in[4];
  const float* bih_f   = (const float*)d_in[5];
  const float* bhh_f   = (const float*)d_in[6];
  const float* Wih_b   = (const float*)d_in[7];
  const float* Whh_b   = (const float*)d_in[8];
  const float* bih_b   = (const float*)d_in[9];
  const float* bhh_b   = (const float*)d_in[10];
  const float* Wp      = (const float*)d_in[11];
  const float* bp      = (const float*)d_in[12];
  const float* ctx     = (const float*)d_in[13];
  const float* Wl      = (const float*)d_in[14];
  const float* bl      = (const float*)d_in[15];
  float* out = (float*)d_out;               // [0,256): logits, [256,65792): attn

  char* ws = (char*)d_ws;
  unsigned short* Wih  = (unsigned short*)(ws + 0);            //   3,145,728
  unsigned short* Whh  = (unsigned short*)(ws + 3145728);      //   3,145,728
  unsigned short* Wpb  = (unsigned short*)(ws + 6291456);      //   1,048,576
  unsigned short* xbf  = (unsigned short*)(ws + 7340032);      //  67,108,864
  unsigned short* outb = (unsigned short*)(ws + 74448896);     // 134,217,728
  unsigned short* hbuf = (unsigned short*)(ws + 208666624);    //     524,288
  float* sc4           = (float*)(ws + 209190912);             //   1,048,576
  unsigned* bar        = (unsigned*)(ws + 210239488);          //       2,048
  // total: 210,241,536 bytes

  k_cast<<<14336, 256, 0, stream>>>(Wih_f, Wih_b, Whh_f, Whh_b, Wp, Wih, Whh, Wpb, bar);
  k_gather<<<16384, 256, 0, stream>>>(tokens, emb, xbf);
  k_rec<<<64, 256, 0, stream>>>(xbf, Wih, Whh, bih_f, bih_b, bhh_f, bhh_b,
                                lengths, hbuf, outb, bar);
  dim3 g2(512, 4);
  k_gemm2<<<g2, 256, 0, stream>>>(outb, Wpb, bp, ctx, sc4);
  k_softmax<<<128, 64, 0, stream>>>(sc4, lengths, out + 256);
  k_final<<<128, 256, 0, stream>>>(out + 256, outb, lengths, Wl, bl, out);
}

// Round 3
// 7648.325 us; speedup vs baseline: 1.3083x; 1.3083x over previous
//
#include <hip/hip_runtime.h>
#include <stdint.h>

#define B_  128
#define T_  512
#define H_  512
#define G3  1536

typedef __attribute__((ext_vector_type(8))) short bf16x8;
typedef __attribute__((ext_vector_type(4))) short bf16x4;
typedef __attribute__((ext_vector_type(4))) float f32x4;

#define MFMA16(a,b,c) __builtin_amdgcn_mfma_f32_16x16x32_bf16((a),(b),(c),0,0,0)

__device__ __forceinline__ unsigned short f2bf(float f) {
  union { float f; unsigned u; } v; v.f = f;
  unsigned r = v.u + 0x7FFFu + ((v.u >> 16) & 1u);
  return (unsigned short)(r >> 16);
}
__device__ __forceinline__ float bf2f(unsigned short u) {
  union { unsigned u; float f; } v; v.u = ((unsigned)u) << 16; return v.f;
}
__device__ __forceinline__ float sigm_f(float x) { return 1.f / (1.f + __expf(-x)); }
__device__ __forceinline__ float tanh_f(float x) { float e = __expf(2.f * x); return 1.f - 2.f / (e + 1.f); }

// coherent (cross-XCD) 8B load/store: relaxed atomics -> per-instruction
// coherence flags, NO acquire/release fences => no whole-L2 inv/wb.
__device__ __forceinline__ unsigned long long cld64(const unsigned short* p) {
  return __hip_atomic_load((const unsigned long long*)p, __ATOMIC_RELAXED,
                           __HIP_MEMORY_SCOPE_SYSTEM);
}
__device__ __forceinline__ void cst64(unsigned short* p, unsigned long long v) {
  __hip_atomic_store((unsigned long long*)p, v, __ATOMIC_RELAXED,
                     __HIP_MEMORY_SCOPE_SYSTEM);
}

// ---------------- K0: cast weights to bf16 + zero the barrier ----------------
__launch_bounds__(256)
__global__ void k_cast(const float* __restrict__ Wih_f, const float* __restrict__ Wih_b,
                       const float* __restrict__ Whh_f, const float* __restrict__ Whh_b,
                       const float* __restrict__ Wp,
                       unsigned short* __restrict__ Wih, unsigned short* __restrict__ Whh,
                       unsigned short* __restrict__ Wpb, unsigned* __restrict__ bar) {
  int idx = blockIdx.x * 256 + threadIdx.x;
  if (idx < 512) bar[idx] = 0;
  if (idx < 1572864) {            // Wih: [2][1536][512]
    float v = (idx < 786432) ? Wih_f[idx] : Wih_b[idx - 786432];
    Wih[idx] = f2bf(v);
  } else if (idx < 3145728) {     // Whh: [2][1536][512]
    int i2 = idx - 1572864;
    float v = (i2 < 786432) ? Whh_f[i2] : Whh_b[i2 - 786432];
    Whh[i2] = f2bf(v);
  } else if (idx < 3670016) {     // Wp: [512][1024]
    int i3 = idx - 3145728;
    Wpb[i3] = f2bf(Wp[i3]);
  }
}

// ---------------- K1: gather embedding -> x_bf [65536][512] ----------------
__launch_bounds__(256)
__global__ void k_gather(const int* __restrict__ tokens, const float* __restrict__ emb,
                         unsigned short* __restrict__ xbf) {
  int row = blockIdx.x * 4 + (threadIdx.x >> 6);
  int lane = threadIdx.x & 63;
  int tok = tokens[row];
  const float4* src = (const float4*)(emb + (size_t)tok * 512);
  float4 v0 = src[lane * 2], v1 = src[lane * 2 + 1];
  bf16x8 pk;
  pk[0] = (short)f2bf(v0.x); pk[1] = (short)f2bf(v0.y);
  pk[2] = (short)f2bf(v0.z); pk[3] = (short)f2bf(v0.w);
  pk[4] = (short)f2bf(v1.x); pk[5] = (short)f2bf(v1.y);
  pk[6] = (short)f2bf(v1.z); pk[7] = (short)f2bf(v1.w);
  *(bf16x8*)&xbf[(size_t)row * 512 + lane * 8] = pk;
}

// ---------------- K2: persistent bidirectional GRU recurrence ----------------
// 128 co-resident blocks: {dir(2)} x {m-half(2)} x {16-dim hidden slice(32)}.
// Per step: (1) x_t @ Wih_slice^T (h-independent, overlaps stragglers),
// (2) tid0 polls per-step counter (relaxed system atomic — NO cache flush),
// (3) h @ Whh_slice^T with h read via coherent u64 loads (bypass stale L2),
// (4) gates in f32 -> LDS repack -> coalesced u64 coherent h-store + u64 outb
// store, (5) __syncthreads (drains vmcnt) then relaxed arrive.
// Weights/x use PLAIN cached loads and stay L2-resident (no invalidation!).
__launch_bounds__(256, 1)
__global__ void k_rec(const unsigned short* __restrict__ xbf,
                      const unsigned short* __restrict__ Wih,
                      const unsigned short* __restrict__ Whh,
                      const float* __restrict__ bih_f, const float* __restrict__ bih_b,
                      const float* __restrict__ bhh_f, const float* __restrict__ bhh_b,
                      const int* __restrict__ lengths,
                      unsigned short* __restrict__ hbuf,   // [2 buf][2 dir][128][512] bf16
                      unsigned short* __restrict__ outb,   // [65536][1024] bf16
                      unsigned* __restrict__ bar) {        // [512] per-step counters
  __shared__ unsigned short htile[4][256];
  __shared__ unsigned short otile[4][256];
  int tid = threadIdx.x;
  int lane = tid & 63, w = tid >> 6;
  int quad = lane >> 4, l15 = lane & 15;
  int bi = blockIdx.x;
  int dir = bi >> 6;
  int mh = (bi >> 5) & 1;
  int j0 = (bi & 31) << 4;
  int jg = j0 + l15;
  int rb = mh * 64 + w * 16;        // this wave's 16 batch rows

  const unsigned short* wih_g = Wih + (size_t)dir * (G3 * H_);
  const unsigned short* whh_g = Whh + (size_t)dir * (G3 * H_);
  const float* bih = dir ? bih_b : bih_f;
  const float* bhh = dir ? bhh_b : bhh_f;
  float b_r  = bih[jg] + bhh[jg];
  float b_z  = bih[512 + jg] + bhh[512 + jg];
  float b_in = bih[1024 + jg];
  float b_hn = bhh[1024 + jg];

  // weight row pointers (lane l15 -> output dim j0+l15)
  const unsigned short* wir = wih_g + (size_t)(jg) * H_;
  const unsigned short* wiz = wih_g + (size_t)(512 + jg) * H_;
  const unsigned short* win = wih_g + (size_t)(1024 + jg) * H_;
  const unsigned short* whr = whh_g + (size_t)(jg) * H_;
  const unsigned short* whz = whh_g + (size_t)(512 + jg) * H_;
  const unsigned short* whn = whh_g + (size_t)(1024 + jg) * H_;

  int b0 = rb + l15;                 // A-frag row
  int L0 = lengths[b0];
  int Lg[4];
  #pragma unroll
  for (int r = 0; r < 4; ++r) Lg[r] = lengths[rb + 4 * quad + r];
  int bs = rb + (lane >> 2);         // store-phase row
  int Ls = lengths[bs];
  int jp = lane & 3;

  unsigned short* hb = hbuf + (size_t)dir * (B_ * H_);
  float hreg[4] = {};                // f32 master copy of own (b, j) hidden state

  for (int t = 0; t < T_; ++t) {
    const unsigned short* hc = hb + (size_t)(t & 1) * (2 * B_ * H_);
    unsigned short* hnx      = hb + (size_t)((t & 1) ^ 1) * (2 * B_ * H_);

    f32x4 acc_r = {0.f,0.f,0.f,0.f}, acc_z = {0.f,0.f,0.f,0.f};
    f32x4 acc_n = {0.f,0.f,0.f,0.f}, acc_h = {0.f,0.f,0.f,0.f};

    // ---- (1) input GEMM for step t (plain cached loads; overlaps stragglers)
    int tx0 = dir ? ((t < L0) ? (L0 - 1 - t) : 0) : t;
    const unsigned short* xr0 = xbf + ((size_t)b0 * T_ + tx0) * 512;
    for (int s = 0; s < 16; ++s) {
      int kb = s * 32 + quad * 8;
      bf16x8 ax = *(const bf16x8*)&xr0[kb];
      acc_r = MFMA16(ax, *(const bf16x8*)&wir[kb], acc_r);
      acc_z = MFMA16(ax, *(const bf16x8*)&wiz[kb], acc_z);
      acc_n = MFMA16(ax, *(const bf16x8*)&win[kb], acc_n);
    }

    // ---- (2) wait for h_{t-1}
    if (t > 0) {
      if (tid == 0) {
        while (__hip_atomic_load(&bar[t - 1], __ATOMIC_RELAXED,
                                 __HIP_MEMORY_SCOPE_SYSTEM) < 128u)
          __builtin_amdgcn_s_sleep(1);
      }
      __syncthreads();
      // ---- (3) hidden GEMM; h read via coherent u64 loads
      const unsigned short* hr0 = hc + (size_t)b0 * H_;
      for (int s = 0; s < 16; ++s) {
        int kb = s * 32 + quad * 8;
        union { unsigned long long q[2]; bf16x8 v; } ah;
        ah.q[0] = cld64(hr0 + kb);
        ah.q[1] = cld64(hr0 + kb + 4);
        acc_r = MFMA16(ah.v, *(const bf16x8*)&whr[kb], acc_r);
        acc_z = MFMA16(ah.v, *(const bf16x8*)&whz[kb], acc_z);
        acc_h = MFMA16(ah.v, *(const bf16x8*)&whn[kb], acc_h);
      }
    }

    // ---- (4) gates -> LDS tile repack
    #pragma unroll
    for (int r = 0; r < 4; ++r) {
      int L = Lg[r];
      bool vld = t < L;
      float rr = sigm_f(acc_r[r] + b_r);
      float zz = sigm_f(acc_z[r] + b_z);
      float nn = tanh_f(acc_n[r] + b_in + rr * (acc_h[r] + b_hn));
      float hold = hreg[r];
      float hnew = vld ? ((1.f - zz) * nn + zz * hold) : hold;
      hreg[r] = hnew;
      unsigned short hbf = f2bf(hnew);
      htile[w][(4 * quad + r) * 16 + l15] = hbf;
      otile[w][(4 * quad + r) * 16 + l15] = vld ? hbf : (unsigned short)0;
    }
    asm volatile("s_waitcnt lgkmcnt(0)" ::: "memory");
    unsigned long long hv = *(const unsigned long long*)&htile[w][(lane >> 2) * 16 + jp * 4];
    unsigned long long ov = *(const unsigned long long*)&otile[w][(lane >> 2) * 16 + jp * 4];
    cst64(&hnx[(size_t)bs * H_ + j0 + jp * 4], hv);
    bool vs = t < Ls;
    int p = dir ? (vs ? (Ls - 1 - t) : t) : t;
    *(unsigned long long*)&outb[((size_t)bs * T_ + p) * 1024 + dir * 512 + j0 + jp * 4] = ov;

    // ---- (5) arrive: __syncthreads drains each wave's vmcnt, then relaxed add
    __syncthreads();
    if (tid == 0)
      __hip_atomic_fetch_add(&bar[t], 1u, __ATOMIC_RELAXED, __HIP_MEMORY_SCOPE_SYSTEM);
  }
}

// ---------------- K3: GEMM2 fused  sc4[cb] = sum_c tanh(out@Wp^T + bp) * ctx ----------------
__launch_bounds__(256)
__global__ void k_gemm2(const unsigned short* __restrict__ outbf,
                        const unsigned short* __restrict__ Wpb,
                        const float* __restrict__ bp, const float* __restrict__ ctx,
                        float* __restrict__ sc4) {     // [4][65536] partials
  __shared__ short smem[2 * 128 * 72];
  short* a_s = smem;
  short* b_s = smem + 128 * 72;
  int tid = threadIdx.x;
  int lane = tid & 63, w = tid >> 6;
  int quad = lane >> 4, l15 = lane & 15;
  int row0 = blockIdx.x * 128, col0 = blockIdx.y * 128;

  f32x4 acc[2][8];
  #pragma unroll
  for (int i = 0; i < 2; ++i)
    #pragma unroll
    for (int j = 0; j < 8; ++j) acc[i][j] = (f32x4){0.f, 0.f, 0.f, 0.f};

  for (int kt = 0; kt < 16; ++kt) {
    int k0 = kt * 64;
    __syncthreads();
    #pragma unroll
    for (int q = 0; q < 4; ++q) {
      int u = tid + 256 * q;
      int r = u >> 3, cu = u & 7;
      *(bf16x8*)&a_s[r * 72 + cu * 8] = *(const bf16x8*)&outbf[(size_t)(row0 + r) * 1024 + k0 + cu * 8];
      *(bf16x8*)&b_s[r * 72 + cu * 8] = *(const bf16x8*)&Wpb[(size_t)(col0 + r) * 1024 + k0 + cu * 8];
    }
    __syncthreads();
    #pragma unroll
    for (int kk = 0; kk < 2; ++kk) {
      int kb = kk * 32 + quad * 8;
      bf16x8 a0 = *(const bf16x8*)&a_s[(w * 32 + l15) * 72 + kb];
      bf16x8 a1 = *(const bf16x8*)&a_s[(w * 32 + 16 + l15) * 72 + kb];
      #pragma unroll
      for (int nt = 0; nt < 8; ++nt) {
        bf16x8 bb = *(const bf16x8*)&b_s[(nt * 16 + l15) * 72 + kb];
        acc[0][nt] = MFMA16(a0, bb, acc[0][nt]);
        acc[1][nt] = MFMA16(a1, bb, acc[1][nt]);
      }
    }
  }

  float rs[2][4] = {};
  #pragma unroll
  for (int mt = 0; mt < 2; ++mt) {
    #pragma unroll
    for (int nt = 0; nt < 8; ++nt) {
      int col = col0 + nt * 16 + l15;
      float bv = bp[col], cv = ctx[col];
      #pragma unroll
      for (int r = 0; r < 4; ++r) {
        float x = acc[mt][nt][r] + bv;
        rs[mt][r] += tanh_f(x) * cv;
      }
    }
  }
  #pragma unroll
  for (int mt = 0; mt < 2; ++mt) {
    #pragma unroll
    for (int r = 0; r < 4; ++r) {
      float v = rs[mt][r];
      v += __shfl_xor(v, 1); v += __shfl_xor(v, 2);
      v += __shfl_xor(v, 4); v += __shfl_xor(v, 8);
      if (l15 == 0)
        sc4[(size_t)blockIdx.y * 65536 + row0 + 32 * w + 16 * mt + 4 * quad + r] = v;
    }
  }
}

// ---------------- K4: masked softmax -> attn (output) ----------------
__launch_bounds__(64)
__global__ void k_softmax(const float* __restrict__ sc4, const int* __restrict__ lengths,
                          float* __restrict__ attn) {
  int b = blockIdx.x, lane = threadIdx.x;
  int L = lengths[b];
  float s[8]; float mx = -1e30f;
  #pragma unroll
  for (int i = 0; i < 8; ++i) {
    int t = lane + i * 64;
    int idx = b * T_ + t;
    float v = -1e30f;
    if (t < L)
      v = sc4[idx] + sc4[65536 + idx] + sc4[131072 + idx] + sc4[196608 + idx];
    s[i] = v;
    mx = fmaxf(mx, v);
  }
  #pragma unroll
  for (int o = 32; o; o >>= 1) mx = fmaxf(mx, __shfl_xor(mx, o));
  float sum = 0.f;
  #pragma unroll
  for (int i = 0; i < 8; ++i) {
    int t = lane + i * 64;
    s[i] = (t < L) ? __expf(s[i] - mx) : 0.f;
    sum += s[i];
  }
  #pragma unroll
  for (int o = 32; o; o >>= 1) sum += __shfl_xor(sum, o);
  float inv = 1.f / sum;
  #pragma unroll
  for (int i = 0; i < 8; ++i) attn[b * T_ + lane + i * 64] = s[i] * inv;
}

// ---------------- K5: attention pool + selu + classifier ----------------
__launch_bounds__(256)
__global__ void k_final(const float* __restrict__ attn, const unsigned short* __restrict__ outb,
                        const int* __restrict__ lengths,
                        const float* __restrict__ Wl, const float* __restrict__ bl,
                        float* __restrict__ logits) {
  __shared__ float red[8];
  int b = blockIdx.x, tid = threadIdx.x;
  int L = lengths[b];
  float a0 = 0.f, a1 = 0.f, a2 = 0.f, a3 = 0.f;
  for (int t = 0; t < L; ++t) {
    float a = attn[b * T_ + t];
    const unsigned short* row = outb + ((size_t)b * T_ + t) * 1024 + tid * 4;
    bf16x4 v = *(const bf16x4*)row;
    a0 += a * bf2f((unsigned short)v[0]);
    a1 += a * bf2f((unsigned short)v[1]);
    a2 += a * bf2f((unsigned short)v[2]);
    a3 += a * bf2f((unsigned short)v[3]);
  }
  const float al = 1.6732632423543772f, sc = 1.0507009873554805f;
  float s0 = sc * (a0 > 0.f ? a0 : al * (__expf(a0) - 1.f));
  float s1 = sc * (a1 > 0.f ? a1 : al * (__expf(a1) - 1.f));
  float s2 = sc * (a2 > 0.f ? a2 : al * (__expf(a2) - 1.f));
  float s3 = sc * (a3 > 0.f ? a3 : al * (__expf(a3) - 1.f));
  int d = tid * 4;
  float p0 = s0 * Wl[d] + s1 * Wl[d + 1] + s2 * Wl[d + 2] + s3 * Wl[d + 3];
  float p1 = s0 * Wl[1024 + d] + s1 * Wl[1024 + d + 1] + s2 * Wl[1024 + d + 2] + s3 * Wl[1024 + d + 3];
  #pragma unroll
  for (int o = 32; o; o >>= 1) { p0 += __shfl_xor(p0, o); p1 += __shfl_xor(p1, o); }
  if ((tid & 63) == 0) { red[(tid >> 6) * 2] = p0; red[(tid >> 6) * 2 + 1] = p1; }
  __syncthreads();
  if (tid == 0) {
    logits[b * 2]     = red[0] + red[2] + red[4] + red[6] + bl[0];
    logits[b * 2 + 1] = red[1] + red[3] + red[5] + red[7] + bl[1];
  }
}

// ---------------- launcher ----------------
extern "C" void kernel_launch(void* const* d_in, const int* in_sizes, int n_in,
                              void* d_out, int out_size, void* d_ws, size_t ws_size,
                              hipStream_t stream) {
  const int*   tokens  = (const int*)d_in[0];
  const int*   lengths = (const int*)d_in[1];
  const float* emb     = (const float*)d_in[2];
  const float* Wih_f   = (const float*)d_in[3];
  const float* Whh_f   = (const float*)d_in[4];
  const float* bih_f   = (const float*)d_in[5];
  const float* bhh_f   = (const float*)d_in[6];
  const float* Wih_b   = (const float*)d_in[7];
  const float* Whh_b   = (const float*)d_in[8];
  const float* bih_b   = (const float*)d_in[9];
  const float* bhh_b   = (const float*)d_in[10];
  const float* Wp      = (const float*)d_in[11];
  const float* bp      = (const float*)d_in[12];
  const float* ctx     = (const float*)d_in[13];
  const float* Wl      = (const float*)d_in[14];
  const float* bl      = (const float*)d_in[15];
  float* out = (float*)d_out;               // [0,256): logits, [256,65792): attn

  char* ws = (char*)d_ws;
  unsigned short* Wih  = (unsigned short*)(ws + 0);            //   3,145,728
  unsigned short* Whh  = (unsigned short*)(ws + 3145728);      //   3,145,728
  unsigned short* Wpb  = (unsigned short*)(ws + 6291456);      //   1,048,576
  unsigned short* xbf  = (unsigned short*)(ws + 7340032);      //  67,108,864
  unsigned short* outb = (unsigned short*)(ws + 74448896);     // 134,217,728
  unsigned short* hbuf = (unsigned short*)(ws + 208666624);    //     524,288
  float* sc4           = (float*)(ws + 209190912);             //   1,048,576
  unsigned* bar        = (unsigned*)(ws + 210239488);          //       2,048
  // total: 210,241,536 bytes

  k_cast<<<14336, 256, 0, stream>>>(Wih_f, Wih_b, Whh_f, Whh_b, Wp, Wih, Whh, Wpb, bar);
  k_gather<<<16384, 256, 0, stream>>>(tokens, emb, xbf);
  k_rec<<<128, 256, 0, stream>>>(xbf, Wih, Whh, bih_f, bih_b, bhh_f, bhh_b,
                                 lengths, hbuf, outb, bar);
  dim3 g2(512, 4);
  k_gemm2<<<g2, 256, 0, stream>>>(outb, Wpb, bp, ctx, sc4);
  k_softmax<<<128, 64, 0, stream>>>(sc4, lengths, out + 256);
  k_final<<<128, 256, 0, stream>>>(out + 256, outb, lengths, Wl, bl, out);
}

// Round 4
// 5406.858 us; speedup vs baseline: 1.8506x; 1.4146x over previous
//
#include <hip/hip_runtime.h>
#include <stdint.h>

#define B_  128
#define T_  512
#define H_  512
#define G3  1536

typedef __attribute__((ext_vector_type(8))) short bf16x8;
typedef __attribute__((ext_vector_type(4))) short bf16x4;
typedef __attribute__((ext_vector_type(4))) float f32x4;

#define MFMA16(a,b,c) __builtin_amdgcn_mfma_f32_16x16x32_bf16((a),(b),(c),0,0,0)

__device__ __forceinline__ unsigned short f2bf(float f) {
  union { float f; unsigned u; } v; v.f = f;
  unsigned r = v.u + 0x7FFFu + ((v.u >> 16) & 1u);
  return (unsigned short)(r >> 16);
}
__device__ __forceinline__ float bf2f(unsigned short u) {
  union { unsigned u; float f; } v; v.u = ((unsigned)u) << 16; return v.f;
}
__device__ __forceinline__ float sigm_f(float x) { return 1.f / (1.f + __expf(-x)); }
__device__ __forceinline__ float tanh_f(float x) { float e = __expf(2.f * x); return 1.f - 2.f / (e + 1.f); }

// coherent (cross-XCD) 8B load/store: relaxed AGENT atomics -> per-instruction
// coherence (bypass stale L1/L2), no fences, no cache maintenance.
__device__ __forceinline__ unsigned long long cld64(const unsigned short* p) {
  return __hip_atomic_load((const unsigned long long*)p, __ATOMIC_RELAXED,
                           __HIP_MEMORY_SCOPE_AGENT);
}
__device__ __forceinline__ void cst64(unsigned short* p, unsigned long long v) {
  __hip_atomic_store((unsigned long long*)p, v, __ATOMIC_RELAXED,
                     __HIP_MEMORY_SCOPE_AGENT);
}

// ---------------- K0: cast weights to bf16 + zero barrier flags ----------------
__launch_bounds__(256)
__global__ void k_cast(const float* __restrict__ Wih_f, const float* __restrict__ Wih_b,
                       const float* __restrict__ Whh_f, const float* __restrict__ Whh_b,
                       const float* __restrict__ Wp,
                       unsigned short* __restrict__ Wih, unsigned short* __restrict__ Whh,
                       unsigned short* __restrict__ Wpb, unsigned* __restrict__ flags) {
  int idx = blockIdx.x * 256 + threadIdx.x;
  if (idx < 65536) flags[idx] = 0;          // [T][128] arrival flags
  if (idx < 1572864) {            // Wih: [2][1536][512]
    float v = (idx < 786432) ? Wih_f[idx] : Wih_b[idx - 786432];
    Wih[idx] = f2bf(v);
  } else if (idx < 3145728) {     // Whh: [2][1536][512]
    int i2 = idx - 1572864;
    float v = (i2 < 786432) ? Whh_f[i2] : Whh_b[i2 - 786432];
    Whh[i2] = f2bf(v);
  } else if (idx < 3670016) {     // Wp: [512][1024]
    int i3 = idx - 3145728;
    Wpb[i3] = f2bf(Wp[i3]);
  }
}

// ---------------- K1: gather embedding -> x_bf [65536][512] ----------------
__launch_bounds__(256)
__global__ void k_gather(const int* __restrict__ tokens, const float* __restrict__ emb,
                         unsigned short* __restrict__ xbf) {
  int row = blockIdx.x * 4 + (threadIdx.x >> 6);
  int lane = threadIdx.x & 63;
  int tok = tokens[row];
  const float4* src = (const float4*)(emb + (size_t)tok * 512);
  float4 v0 = src[lane * 2], v1 = src[lane * 2 + 1];
  bf16x8 pk;
  pk[0] = (short)f2bf(v0.x); pk[1] = (short)f2bf(v0.y);
  pk[2] = (short)f2bf(v0.z); pk[3] = (short)f2bf(v0.w);
  pk[4] = (short)f2bf(v1.x); pk[5] = (short)f2bf(v1.y);
  pk[6] = (short)f2bf(v1.z); pk[7] = (short)f2bf(v1.w);
  *(bf16x8*)&xbf[(size_t)row * 512 + lane * 8] = pk;
}

// ---------------- K2: persistent bidirectional GRU recurrence ----------------
// 128 co-resident blocks. Role derived from a XCD-clustering swizzle
// (bi&7 = XCD under round-robin dispatch, perf heuristic only): each
// (dir, m-half) group of 32 j-slice blocks lands on 2 XCDs -> x rows are
// fetched into 2 L2s instead of 8.
// Barrier: RMW-free. Producer block stores flags[t][dir*64+ord]=1 (relaxed
// agent store, issued after __syncthreads drained its coherent h stores).
// Waiter: wave 0's 64 lanes each poll one flag, __ballot until all set.
// Whh fragments live in registers (192 VGPRs) -> post-barrier critical path
// is just 32 coherent h loads + 48 MFMAs + gates.
__launch_bounds__(256, 1)
__global__ void k_rec(const unsigned short* __restrict__ xbf,
                      const unsigned short* __restrict__ Wih,
                      const unsigned short* __restrict__ Whh,
                      const float* __restrict__ bih_f, const float* __restrict__ bih_b,
                      const float* __restrict__ bhh_f, const float* __restrict__ bhh_b,
                      const int* __restrict__ lengths,
                      unsigned short* __restrict__ hbuf,   // [2 buf][2 dir][128][512] bf16
                      unsigned short* __restrict__ outb,   // [65536][1024] bf16
                      unsigned* __restrict__ flags) {      // [512][128]
  __shared__ unsigned short htile[4][256];
  __shared__ unsigned short otile[4][256];
  int tid = threadIdx.x;
  int lane = tid & 63, w = tid >> 6;
  int quad = lane >> 4, l15 = lane & 15;

  int bi = blockIdx.x;
  int xcd = bi & 7, slot = bi >> 3;       // round-robin XCD heuristic
  int grp = xcd >> 1;                     // 4 groups x 2 XCDs
  int dir = grp >> 1, mh = grp & 1;
  int j5 = slot | ((xcd & 1) << 4);       // 0..31 hidden slice
  int j0 = j5 << 4;
  int jg = j0 + l15;
  int ord = (mh << 5) | j5;               // within-dir ordinal 0..63
  int rb = mh * 64 + w * 16;              // this wave's 16 batch rows

  const unsigned short* wih_g = Wih + (size_t)dir * (G3 * H_);
  const unsigned short* whh_g = Whh + (size_t)dir * (G3 * H_);
  const float* bih = dir ? bih_b : bih_f;
  const float* bhh = dir ? bhh_b : bhh_f;
  float b_r  = bih[jg] + bhh[jg];
  float b_z  = bih[512 + jg] + bhh[512 + jg];
  float b_in = bih[1024 + jg];
  float b_hn = bhh[1024 + jg];

  const unsigned short* wir = wih_g + (size_t)(jg) * H_;
  const unsigned short* wiz = wih_g + (size_t)(512 + jg) * H_;
  const unsigned short* win = wih_g + (size_t)(1024 + jg) * H_;
  const unsigned short* whr = whh_g + (size_t)(jg) * H_;
  const unsigned short* whz = whh_g + (size_t)(512 + jg) * H_;
  const unsigned short* whn = whh_g + (size_t)(1024 + jg) * H_;

  // hoist Whh B-fragments into registers (48 x bf16x8 = 192 VGPRs)
  bf16x8 whr_r[16], whz_r[16], whn_r[16];
  #pragma unroll
  for (int s = 0; s < 16; ++s) {
    int kb = s * 32 + quad * 8;
    whr_r[s] = *(const bf16x8*)&whr[kb];
    whz_r[s] = *(const bf16x8*)&whz[kb];
    whn_r[s] = *(const bf16x8*)&whn[kb];
  }

  int b0 = rb + l15;                 // A-frag row
  int L0 = lengths[b0];
  int Lg[4];
  #pragma unroll
  for (int r = 0; r < 4; ++r) Lg[r] = lengths[rb + 4 * quad + r];
  int bs = rb + (lane >> 2);         // store-phase row
  int Ls = lengths[bs];
  int jp = lane & 3;

  unsigned short* hb = hbuf + (size_t)dir * (B_ * H_);
  float hreg[4] = {};                // f32 master copy of own (b, j) hidden state

  for (int t = 0; t < T_; ++t) {
    const unsigned short* hc = hb + (size_t)(t & 1) * (2 * B_ * H_);
    unsigned short* hnx      = hb + (size_t)((t & 1) ^ 1) * (2 * B_ * H_);

    f32x4 acc_r = {0.f,0.f,0.f,0.f}, acc_z = {0.f,0.f,0.f,0.f};
    f32x4 acc_n = {0.f,0.f,0.f,0.f}, acc_h = {0.f,0.f,0.f,0.f};

    // ---- (1) input GEMM for step t (plain cached loads; h-independent)
    int tx0 = dir ? ((t < L0) ? (L0 - 1 - t) : 0) : t;
    const unsigned short* xr0 = xbf + ((size_t)b0 * T_ + tx0) * 512;
    for (int s = 0; s < 16; ++s) {
      int kb = s * 32 + quad * 8;
      bf16x8 ax = *(const bf16x8*)&xr0[kb];
      acc_r = MFMA16(ax, *(const bf16x8*)&wir[kb], acc_r);
      acc_z = MFMA16(ax, *(const bf16x8*)&wiz[kb], acc_z);
      acc_n = MFMA16(ax, *(const bf16x8*)&win[kb], acc_n);
    }

    // ---- (2) wait for h_{t-1}: 64 lanes of wave 0 poll this dir's 64 flags
    if (t > 0) {
      if (w == 0) {
        const unsigned* fp = &flags[(size_t)(t - 1) * 128 + dir * 64];
        unsigned v;
        do {
          v = __hip_atomic_load(&fp[lane], __ATOMIC_RELAXED, __HIP_MEMORY_SCOPE_AGENT);
        } while (__ballot(v != 0) != 0xFFFFFFFFFFFFFFFFull);
      }
      __syncthreads();
      // ---- (3) hidden GEMM; h via coherent u64 loads, Whh from registers
      const unsigned short* hr0 = hc + (size_t)b0 * H_;
      #pragma unroll
      for (int s = 0; s < 16; ++s) {
        int kb = s * 32 + quad * 8;
        union { unsigned long long q[2]; bf16x8 v; } ah;
        ah.q[0] = cld64(hr0 + kb);
        ah.q[1] = cld64(hr0 + kb + 4);
        acc_r = MFMA16(ah.v, whr_r[s], acc_r);
        acc_z = MFMA16(ah.v, whz_r[s], acc_z);
        acc_h = MFMA16(ah.v, whn_r[s], acc_h);
      }
    }

    // ---- (4) gates -> LDS tile repack -> coalesced u64 stores
    #pragma unroll
    for (int r = 0; r < 4; ++r) {
      int L = Lg[r];
      bool vld = t < L;
      float rr = sigm_f(acc_r[r] + b_r);
      float zz = sigm_f(acc_z[r] + b_z);
      float nn = tanh_f(acc_n[r] + b_in + rr * (acc_h[r] + b_hn));
      float hold = hreg[r];
      float hnew = vld ? ((1.f - zz) * nn + zz * hold) : hold;
      hreg[r] = hnew;
      unsigned short hbf = f2bf(hnew);
      htile[w][(4 * quad + r) * 16 + l15] = hbf;
      otile[w][(4 * quad + r) * 16 + l15] = vld ? hbf : (unsigned short)0;
    }
    asm volatile("s_waitcnt lgkmcnt(0)" ::: "memory");
    unsigned long long hv = *(const unsigned long long*)&htile[w][(lane >> 2) * 16 + jp * 4];
    unsigned long long ov = *(const unsigned long long*)&otile[w][(lane >> 2) * 16 + jp * 4];
    cst64(&hnx[(size_t)bs * H_ + j0 + jp * 4], hv);
    bool vs = t < Ls;
    int p = dir ? (vs ? (Ls - 1 - t) : t) : t;
    *(unsigned long long*)&outb[((size_t)bs * T_ + p) * 1024 + dir * 512 + j0 + jp * 4] = ov;

    // ---- (5) arrive: __syncthreads drains vmcnt (h stores visible), then flag
    __syncthreads();
    if (tid == 0)
      __hip_atomic_store(&flags[(size_t)t * 128 + dir * 64 + ord], 1u,
                         __ATOMIC_RELAXED, __HIP_MEMORY_SCOPE_AGENT);
  }
}

// ---------------- K3: GEMM2 fused  sc4[cb] = sum_c tanh(out@Wp^T + bp) * ctx ----------------
__launch_bounds__(256)
__global__ void k_gemm2(const unsigned short* __restrict__ outbf,
                        const unsigned short* __restrict__ Wpb,
                        const float* __restrict__ bp, const float* __restrict__ ctx,
                        float* __restrict__ sc4) {     // [4][65536] partials
  __shared__ short smem[2 * 128 * 72];
  short* a_s = smem;
  short* b_s = smem + 128 * 72;
  int tid = threadIdx.x;
  int lane = tid & 63, w = tid >> 6;
  int quad = lane >> 4, l15 = lane & 15;
  int row0 = blockIdx.x * 128, col0 = blockIdx.y * 128;

  f32x4 acc[2][8];
  #pragma unroll
  for (int i = 0; i < 2; ++i)
    #pragma unroll
    for (int j = 0; j < 8; ++j) acc[i][j] = (f32x4){0.f, 0.f, 0.f, 0.f};

  for (int kt = 0; kt < 16; ++kt) {
    int k0 = kt * 64;
    __syncthreads();
    #pragma unroll
    for (int q = 0; q < 4; ++q) {
      int u = tid + 256 * q;
      int r = u >> 3, cu = u & 7;
      *(bf16x8*)&a_s[r * 72 + cu * 8] = *(const bf16x8*)&outbf[(size_t)(row0 + r) * 1024 + k0 + cu * 8];
      *(bf16x8*)&b_s[r * 72 + cu * 8] = *(const bf16x8*)&Wpb[(size_t)(col0 + r) * 1024 + k0 + cu * 8];
    }
    __syncthreads();
    #pragma unroll
    for (int kk = 0; kk < 2; ++kk) {
      int kb = kk * 32 + quad * 8;
      bf16x8 a0 = *(const bf16x8*)&a_s[(w * 32 + l15) * 72 + kb];
      bf16x8 a1 = *(const bf16x8*)&a_s[(w * 32 + 16 + l15) * 72 + kb];
      #pragma unroll
      for (int nt = 0; nt < 8; ++nt) {
        bf16x8 bb = *(const bf16x8*)&b_s[(nt * 16 + l15) * 72 + kb];
        acc[0][nt] = MFMA16(a0, bb, acc[0][nt]);
        acc[1][nt] = MFMA16(a1, bb, acc[1][nt]);
      }
    }
  }

  float rs[2][4] = {};
  #pragma unroll
  for (int mt = 0; mt < 2; ++mt) {
    #pragma unroll
    for (int nt = 0; nt < 8; ++nt) {
      int col = col0 + nt * 16 + l15;
      float bv = bp[col], cv = ctx[col];
      #pragma unroll
      for (int r = 0; r < 4; ++r) {
        float x = acc[mt][nt][r] + bv;
        rs[mt][r] += tanh_f(x) * cv;
      }
    }
  }
  #pragma unroll
  for (int mt = 0; mt < 2; ++mt) {
    #pragma unroll
    for (int r = 0; r < 4; ++r) {
      float v = rs[mt][r];
      v += __shfl_xor(v, 1); v += __shfl_xor(v, 2);
      v += __shfl_xor(v, 4); v += __shfl_xor(v, 8);
      if (l15 == 0)
        sc4[(size_t)blockIdx.y * 65536 + row0 + 32 * w + 16 * mt + 4 * quad + r] = v;
    }
  }
}

// ---------------- K4: masked softmax -> attn (output) ----------------
__launch_bounds__(64)
__global__ void k_softmax(const float* __restrict__ sc4, const int* __restrict__ lengths,
                          float* __restrict__ attn) {
  int b = blockIdx.x, lane = threadIdx.x;
  int L = lengths[b];
  float s[8]; float mx = -1e30f;
  #pragma unroll
  for (int i = 0; i < 8; ++i) {
    int t = lane + i * 64;
    int idx = b * T_ + t;
    float v = -1e30f;
    if (t < L)
      v = sc4[idx] + sc4[65536 + idx] + sc4[131072 + idx] + sc4[196608 + idx];
    s[i] = v;
    mx = fmaxf(mx, v);
  }
  #pragma unroll
  for (int o = 32; o; o >>= 1) mx = fmaxf(mx, __shfl_xor(mx, o));
  float sum = 0.f;
  #pragma unroll
  for (int i = 0; i < 8; ++i) {
    int t = lane + i * 64;
    s[i] = (t < L) ? __expf(s[i] - mx) : 0.f;
    sum += s[i];
  }
  #pragma unroll
  for (int o = 32; o; o >>= 1) sum += __shfl_xor(sum, o);
  float inv = 1.f / sum;
  #pragma unroll
  for (int i = 0; i < 8; ++i) attn[b * T_ + lane + i * 64] = s[i] * inv;
}

// ---------------- K5: attention pool + selu + classifier ----------------
__launch_bounds__(256)
__global__ void k_final(const float* __restrict__ attn, const unsigned short* __restrict__ outb,
                        const int* __restrict__ lengths,
                        const float* __restrict__ Wl, const float* __restrict__ bl,
                        float* __restrict__ logits) {
  __shared__ float red[8];
  int b = blockIdx.x, tid = threadIdx.x;
  int L = lengths[b];
  float a0 = 0.f, a1 = 0.f, a2 = 0.f, a3 = 0.f;
  for (int t = 0; t < L; ++t) {
    float a = attn[b * T_ + t];
    const unsigned short* row = outb + ((size_t)b * T_ + t) * 1024 + tid * 4;
    bf16x4 v = *(const bf16x4*)row;
    a0 += a * bf2f((unsigned short)v[0]);
    a1 += a * bf2f((unsigned short)v[1]);
    a2 += a * bf2f((unsigned short)v[2]);
    a3 += a * bf2f((unsigned short)v[3]);
  }
  const float al = 1.6732632423543772f, sc = 1.0507009873554805f;
  float s0 = sc * (a0 > 0.f ? a0 : al * (__expf(a0) - 1.f));
  float s1 = sc * (a1 > 0.f ? a1 : al * (__expf(a1) - 1.f));
  float s2 = sc * (a2 > 0.f ? a2 : al * (__expf(a2) - 1.f));
  float s3 = sc * (a3 > 0.f ? a3 : al * (__expf(a3) - 1.f));
  int d = tid * 4;
  float p0 = s0 * Wl[d] + s1 * Wl[d + 1] + s2 * Wl[d + 2] + s3 * Wl[d + 3];
  float p1 = s0 * Wl[1024 + d] + s1 * Wl[1024 + d + 1] + s2 * Wl[1024 + d + 2] + s3 * Wl[1024 + d + 3];
  #pragma unroll
  for (int o = 32; o; o >>= 1) { p0 += __shfl_xor(p0, o); p1 += __shfl_xor(p1, o); }
  if ((tid & 63) == 0) { red[(tid >> 6) * 2] = p0; red[(tid >> 6) * 2 + 1] = p1; }
  __syncthreads();
  if (tid == 0) {
    logits[b * 2]     = red[0] + red[2] + red[4] + red[6] + bl[0];
    logits[b * 2 + 1] = red[1] + red[3] + red[5] + red[7] + bl[1];
  }
}

// ---------------- launcher ----------------
extern "C" void kernel_launch(void* const* d_in, const int* in_sizes, int n_in,
                              void* d_out, int out_size, void* d_ws, size_t ws_size,
                              hipStream_t stream) {
  const int*   tokens  = (const int*)d_in[0];
  const int*   lengths = (const int*)d_in[1];
  const float* emb     = (const float*)d_in[2];
  const float* Wih_f   = (const float*)d_in[3];
  const float* Whh_f   = (const float*)d_in[4];
  const float* bih_f   = (const float*)d_in[5];
  const float* bhh_f   = (const float*)d_in[6];
  const float* Wih_b   = (const float*)d_in[7];
  const float* Whh_b   = (const float*)d_in[8];
  const float* bih_b   = (const float*)d_in[9];
  const float* bhh_b   = (const float*)d_in[10];
  const float* Wp      = (const float*)d_in[11];
  const float* bp      = (const float*)d_in[12];
  const float* ctx     = (const float*)d_in[13];
  const float* Wl      = (const float*)d_in[14];
  const float* bl      = (const float*)d_in[15];
  float* out = (float*)d_out;               // [0,256): logits, [256,65792): attn

  char* ws = (char*)d_ws;
  unsigned short* Wih  = (unsigned short*)(ws + 0);            //   3,145,728
  unsigned short* Whh  = (unsigned short*)(ws + 3145728);      //   3,145,728
  unsigned short* Wpb  = (unsigned short*)(ws + 6291456);      //   1,048,576
  unsigned short* xbf  = (unsigned short*)(ws + 7340032);      //  67,108,864
  unsigned short* outb = (unsigned short*)(ws + 74448896);     // 134,217,728
  unsigned short* hbuf = (unsigned short*)(ws + 208666624);    //     524,288
  float* sc4           = (float*)(ws + 209190912);             //   1,048,576
  unsigned* flags      = (unsigned*)(ws + 210239488);          //     262,144
  // total: 210,501,632 bytes

  k_cast<<<14336, 256, 0, stream>>>(Wih_f, Wih_b, Whh_f, Whh_b, Wp, Wih, Whh, Wpb, flags);
  k_gather<<<16384, 256, 0, stream>>>(tokens, emb, xbf);
  k_rec<<<128, 256, 0, stream>>>(xbf, Wih, Whh, bih_f, bih_b, bhh_f, bhh_b,
                                 lengths, hbuf, outb, flags);
  dim3 g2(512, 4);
  k_gemm2<<<g2, 256, 0, stream>>>(outb, Wpb, bp, ctx, sc4);
  k_softmax<<<128, 64, 0, stream>>>(sc4, lengths, out + 256);
  k_final<<<128, 256, 0, stream>>>(out + 256, outb, lengths, Wl, bl, out);
}